// Round 2
// baseline (254.546 us; speedup 1.0000x reference)
//
#include <hip/hip_runtime.h>
#include <math.h>

// GATv2 (in_ch=1, edge_dim=1, H=2, C=64) + fc, collapsed to rank-1/rank-2 algebra.
//
// Round 7 (= round 6 resubmit after infra failure): k_reduce split P=4 ways
// per bucket (grid 782 -> 3128 blocks, 3.05 -> 12.2 blocks/CU) to fix the 26%
// occupancy latency wall, and the per-record binary search (8-10 dependent LDS
// reads) replaced by an LDS record-index LUT (1 LDS read per record). Each
// part writes a 128x6 partial slab; k_fin sums P partials and runs the old
// finalize (self-loop + softmax-S) epilogue.
//
// ws: rec[S_BLOCKS*2048] int4 | offsT[(NB+1)*S_BLOCKS] int | S[2N] f32 |
//     C[1152] f32 | Spart[NB*P*128*6] f32

#define LRELU_A1 0.6f   // leakyrelu(v) = 0.6 v + 0.4 |v|  (slope 0.2)
#define LRELU_A2 0.4f
#define TB       256
#define EPB      2048   // edges per bin block
#define NPB      128    // nodes per bucket (dst>>7)
#define NB_MAX   1024
#define SB_MAX   1024
#define LUTSZ    2048   // record-index LUT entries per window

__global__ void k_prep(const unsigned int* __restrict__ ei,
                       const float* __restrict__ att,
                       const float* __restrict__ W_l,
                       const float* __restrict__ b_l, const float* __restrict__ b_r,
                       const float* __restrict__ bias_out,
                       const float* __restrict__ W_fc, const float* __restrict__ b_fc,
                       float* __restrict__ C) {
  int j = threadIdx.x;
  unsigned long long nz = __ballot(j < 32 && ei[2 * j + 1] != 0u);
  if (j == 0) ((int*)C)[1024] = (nz == 0ull) ? 1 : 0;   // 1 => int64 indices
  if (j >= 128) return;
  float a = att[j];
  C[j] = LRELU_A1 * a;          // A1
  C[128 + j] = LRELU_A2 * a;    // A2
  C[256 + j] = b_l[j] + b_r[j]; // BASE
  const float* wrow = W_fc + j * 256;
  float u0 = 0.f, u1 = 0.f, v0 = 0.f, v1 = 0.f, cb = b_fc[j];
  for (int c = 0; c < 64; c++) {
    u0 = fmaf(W_l[c],      wrow[c],       u0);
    u1 = fmaf(W_l[64 + c], wrow[64 + c],  u1);
    v0 = fmaf(W_l[c],      wrow[128 + c], v0);
    v1 = fmaf(W_l[64 + c], wrow[192 + c], v1);
  }
  for (int t = 0; t < 128; t++) {
    float gb = b_l[t] + bias_out[t];
    cb = fmaf(gb, wrow[t] + wrow[128 + t], cb);
  }
  C[384 + j] = u0;  // U0
  C[512 + j] = u1;  // U1
  C[640 + j] = v0;  // V0
  C[768 + j] = v1;  // V1
  C[896 + j] = cb;  // CB
}

#define CH_STEP(comp, ACC, i)                                                      \
  do {                                                                             \
    float v_ = fmaf(xs8[i], wl.comp, fmaf(xt8[i], wr.comp, fmaf(ae8[i], we.comp, bb.comp))); \
    ACC[i] = fmaf(a2.comp, fabsf(v_), fmaf(a1.comp, v_, ACC[i]));                  \
  } while (0)

__global__ __launch_bounds__(TB, 4) void k_bin(
    const float* __restrict__ x, const int* __restrict__ ei,
    const float* __restrict__ ea,
    const float* __restrict__ WL, const float* __restrict__ WR,
    const float* __restrict__ WE, const float* __restrict__ C,
    int4* __restrict__ rec, int* __restrict__ offsT,
    int NB, int S_BLOCKS, int E) {
  __shared__ int cnt[NB_MAX];
  __shared__ int pfx[NB_MAX + 1];
  __shared__ int sc[TB];
  const int tid = threadIdx.x;
  for (int i = tid; i < NB_MAX; i += TB) cnt[i] = 0;
  __syncthreads();

  const int e0 = blockIdx.x * EPB;
  const bool w64 = ((const int*)C)[1024] != 0;
  const float* A1 = C;
  const float* A2 = C + 128;
  const float* BASE = C + 256;

  int de8[8];
  float ae8[8], xs8[8], xt8[8];
  bool ok[8];
#pragma unroll
  for (int i = 0; i < 8; i++) {
    int e = e0 + i * TB + tid;   // coalesced per round
    ok[i] = (e < E);
    int ee = ok[i] ? e : 0;
    int s_ = w64 ? ei[2 * ee] : ei[ee];
    int d_ = w64 ? ei[2 * (E + ee)] : ei[E + ee];
    de8[i] = d_;
    ae8[i] = ea[ee];
    xs8[i] = x[s_];
    xt8[i] = x[d_];
  }
  float acc0[8] = {0.f, 0.f, 0.f, 0.f, 0.f, 0.f, 0.f, 0.f};
  float acc1[8] = {0.f, 0.f, 0.f, 0.f, 0.f, 0.f, 0.f, 0.f};
#pragma unroll 2
  for (int jb = 0; jb < 64; jb += 4) {
    float4 wl = *(const float4*)(WL + jb);
    float4 wr = *(const float4*)(WR + jb);
    float4 we = *(const float4*)(WE + jb);
    float4 bb = *(const float4*)(BASE + jb);
    float4 a1 = *(const float4*)(A1 + jb);
    float4 a2 = *(const float4*)(A2 + jb);
#pragma unroll
    for (int i = 0; i < 8; i++) {
      CH_STEP(x, acc0, i); CH_STEP(y, acc0, i); CH_STEP(z, acc0, i); CH_STEP(w, acc0, i);
    }
  }
#pragma unroll 2
  for (int jb = 64; jb < 128; jb += 4) {
    float4 wl = *(const float4*)(WL + jb);
    float4 wr = *(const float4*)(WR + jb);
    float4 we = *(const float4*)(WE + jb);
    float4 bb = *(const float4*)(BASE + jb);
    float4 a1 = *(const float4*)(A1 + jb);
    float4 a2 = *(const float4*)(A2 + jb);
#pragma unroll
    for (int i = 0; i < 8; i++) {
      CH_STEP(x, acc1, i); CH_STEP(y, acc1, i); CH_STEP(z, acc1, i); CH_STEP(w, acc1, i);
    }
  }
  // payload -> registers; claim slots in LDS
  int b8[8], slot8[8], p0[8], p1[8], p2[8], p3[8];
#pragma unroll
  for (int i = 0; i < 8; i++) {
    int d_ = de8[i];
    b8[i] = d_ >> 7;
    p0[i] = __float_as_int(__expf(acc0[i]));
    p1[i] = __float_as_int(__expf(acc1[i]));
    p2[i] = __float_as_int(xs8[i]);
    p3[i] = (int)((__float_as_uint(ae8[i]) & ~127u) | (unsigned)(d_ & 127));
    slot8[i] = ok[i] ? atomicAdd(&cnt[b8[i]], 1) : 0;
  }
  __syncthreads();
  // two-level exclusive scan of cnt[0..NB)
  int l4[4], mysum = 0;
#pragma unroll
  for (int j = 0; j < 4; j++) {
    int idx = tid * 4 + j;
    l4[j] = (idx < NB) ? cnt[idx] : 0;
    mysum += l4[j];
  }
  sc[tid] = mysum;
  __syncthreads();
  for (int st = 1; st < TB; st <<= 1) {
    int v = (tid >= st) ? sc[tid - st] : 0;
    __syncthreads();
    sc[tid] += v;
    __syncthreads();
  }
  int run = sc[tid] - mysum;
#pragma unroll
  for (int j = 0; j < 4; j++) {
    int idx = tid * 4 + j;
    if (idx < NB) { pfx[idx] = run; run += l4[j]; }
  }
  if (tid == 0) pfx[NB] = sc[TB - 1];
  __syncthreads();
  for (int b = tid; b <= NB; b += TB)
    offsT[(size_t)b * S_BLOCKS + blockIdx.x] = pfx[b];
  // direct-indexed drain from registers (random within 32KB block region; L2-local)
  int4* myrec = rec + (size_t)blockIdx.x * EPB;
#pragma unroll
  for (int i = 0; i < 8; i++) {
    if (ok[i]) myrec[pfx[b8[i]] + slot8[i]] = make_int4(p0[i], p1[i], p2[i], p3[i]);
  }
}

// One block per (bucket, part). part covers segments s in
// [part*SPP, min((part+1)*SPP, S_BLOCKS)). Balanced gather via LDS LUT of
// global rec indices (1 LDS read/record instead of 8-10 dep binary-search
// reads). Writes 128x6 partial accumulators to Spart; no finalize here.
__global__ __launch_bounds__(TB, 8) void k_reduce(
    const int4* __restrict__ rec, const int* __restrict__ offsT,
    float* __restrict__ Spart, int S_BLOCKS, int SPP) {
  __shared__ float lacc[NPB * 7];      // stride 7, bank-friendly
  __shared__ int sc[TB];
  __shared__ int lut[LUTSZ];
  const int tid = threadIdx.x;
  const int b = blockIdx.x;            // bucket
  const int part = blockIdx.y;
  for (int i = tid; i < NPB * 7; i += TB) lacc[i] = 0.f;

  // each thread owns up to 4 local segments (supports SPP <= 1024)
  int l4[4], rb4[4];
  int mysum = 0;
#pragma unroll
  for (int j = 0; j < 4; j++) {
    int sidx = tid * 4 + j;
    int s = part * SPP + sidx;
    int st = 0, len = 0;
    if (sidx < SPP && s < S_BLOCKS) {
      st  = offsT[(size_t)b * S_BLOCKS + s];
      len = offsT[(size_t)(b + 1) * S_BLOCKS + s] - st;
    }
    rb4[j] = s * EPB + st;   // global rec index of this segment's first record
    l4[j] = len;
    mysum += len;
  }
  sc[tid] = mysum;
  __syncthreads();
  for (int d = 1; d < TB; d <<= 1) {
    int v = (tid >= d) ? sc[tid - d] : 0;
    __syncthreads();
    sc[tid] += v;
    __syncthreads();
  }
  const int T = sc[TB - 1];
  int run = sc[tid] - mysum;
  int bs4[4];
#pragma unroll
  for (int j = 0; j < 4; j++) { bs4[j] = run; run += l4[j]; }

  for (int w0 = 0; w0 < T; w0 += LUTSZ) {
    const int w1 = min(w0 + LUTSZ, T);
    // fill lut[w0..w1): each segment-owner scatters its records' rec indices
#pragma unroll
    for (int j = 0; j < 4; j++) {
      int lo = max(bs4[j], w0), hi = min(bs4[j] + l4[j], w1);
      for (int k = lo; k < hi; k++) lut[k - w0] = rb4[j] + (k - bs4[j]);
    }
    __syncthreads();
    for (int i = w0 + tid; i < w1; i += TB) {
      int4 r = rec[(size_t)(unsigned)lut[i - w0]];
      float e0v = __int_as_float(r.x);
      float e1v = __int_as_float(r.y);
      float xsv = __int_as_float(r.z);
      unsigned eab = (unsigned)r.w;
      float* a = lacc + (int)(eab & 127u) * 7;
      float aev = __uint_as_float(eab & ~127u);
      atomicAdd(a + 0, e0v);
      atomicAdd(a + 1, e0v * xsv);
      atomicAdd(a + 2, e1v);
      atomicAdd(a + 3, e1v * xsv);
      atomicAdd(a + 4, aev);
      atomicAdd(a + 5, 1.0f);
    }
    __syncthreads();
  }
  __syncthreads();
  // drain partials: 768 floats, coalesced
  float* out = Spart + ((size_t)b * gridDim.y + part) * (NPB * 6);
  for (int u = tid; u < NPB * 6; u += TB)
    out[u] = lacc[(u / 6) * 7 + (u % 6)];
}

// Sum the P partials per node, then fused self-loop + S finalize (moved from
// the old k_reduce tail). One thread per node.
__global__ __launch_bounds__(256) void k_fin(
    const float* __restrict__ x,
    const float* __restrict__ WL, const float* __restrict__ WR,
    const float* __restrict__ WE, const float* __restrict__ C,
    const float* __restrict__ Spart, float* __restrict__ S,
    int N, int P) {
  int n = blockIdx.x * blockDim.x + threadIdx.x;
  if (n >= N) return;
  int b = n >> 7, t = n & 127;
  const float* q0 = Spart + ((size_t)b * P) * (NPB * 6) + t * 6;
  float den0 = 0.f, num0 = 0.f, den1 = 0.f, num1 = 0.f, asum = 0.f, cntv = 0.f;
  for (int p = 0; p < P; p++) {
    const float* q = q0 + (size_t)p * (NPB * 6);
    float2 v0 = *(const float2*)(q);
    float2 v1 = *(const float2*)(q + 2);
    float2 v2 = *(const float2*)(q + 4);
    den0 += v0.x; num0 += v0.y;
    den1 += v1.x; num1 += v1.y;
    asum += v2.x; cntv += v2.y;
  }
  const float* A1 = C;
  const float* A2 = C + 128;
  const float* BASE = C + 256;
  float xn = x[n];
  float am = asum / fmaxf(cntv, 1.0f);
  float acc0 = 0.f, acc1 = 0.f;
#pragma unroll 4
  for (int jb = 0; jb < 64; jb += 4) {
    float4 wl = *(const float4*)(WL + jb);
    float4 wr = *(const float4*)(WR + jb);
    float4 we = *(const float4*)(WE + jb);
    float4 bb = *(const float4*)(BASE + jb);
    float4 a1 = *(const float4*)(A1 + jb);
    float4 a2 = *(const float4*)(A2 + jb);
    float v;
    v = fmaf(xn, wl.x + wr.x, fmaf(am, we.x, bb.x)); acc0 = fmaf(a2.x, fabsf(v), fmaf(a1.x, v, acc0));
    v = fmaf(xn, wl.y + wr.y, fmaf(am, we.y, bb.y)); acc0 = fmaf(a2.y, fabsf(v), fmaf(a1.y, v, acc0));
    v = fmaf(xn, wl.z + wr.z, fmaf(am, we.z, bb.z)); acc0 = fmaf(a2.z, fabsf(v), fmaf(a1.z, v, acc0));
    v = fmaf(xn, wl.w + wr.w, fmaf(am, we.w, bb.w)); acc0 = fmaf(a2.w, fabsf(v), fmaf(a1.w, v, acc0));
  }
#pragma unroll 4
  for (int jb = 64; jb < 128; jb += 4) {
    float4 wl = *(const float4*)(WL + jb);
    float4 wr = *(const float4*)(WR + jb);
    float4 we = *(const float4*)(WE + jb);
    float4 bb = *(const float4*)(BASE + jb);
    float4 a1 = *(const float4*)(A1 + jb);
    float4 a2 = *(const float4*)(A2 + jb);
    float v;
    v = fmaf(xn, wl.x + wr.x, fmaf(am, we.x, bb.x)); acc1 = fmaf(a2.x, fabsf(v), fmaf(a1.x, v, acc1));
    v = fmaf(xn, wl.y + wr.y, fmaf(am, we.y, bb.y)); acc1 = fmaf(a2.y, fabsf(v), fmaf(a1.y, v, acc1));
    v = fmaf(xn, wl.z + wr.z, fmaf(am, we.z, bb.z)); acc1 = fmaf(a2.z, fabsf(v), fmaf(a1.z, v, acc1));
    v = fmaf(xn, wl.w + wr.w, fmaf(am, we.w, bb.w)); acc1 = fmaf(a2.w, fabsf(v), fmaf(a1.w, v, acc1));
  }
  float s0 = __expf(acc0), s1 = __expf(acc1);
  float2 sv;
  sv.x = (num0 + s0 * xn) / (den0 + s0);
  sv.y = (num1 + s1 * xn) / (den1 + s1);
  *(float2*)(S + 2 * n) = sv;
}

__global__ __launch_bounds__(256) void k_out(
    const float* __restrict__ S, const float* __restrict__ C,
    const int* __restrict__ tgtp, float* __restrict__ out, int N) {
  int g = blockIdx.x * blockDim.x + threadIdx.x;
  if (g >= N * 32) return;
  int n = g >> 5;
  int kq = (g & 31) * 4;
  int T = tgtp[0];  // low word valid for int32 and little-endian int64
  float s0t = S[2 * T], s1t = S[2 * T + 1];
  float2 s = *(const float2*)(S + 2 * n);
  float4 u0 = *(const float4*)(C + 384 + kq);
  float4 u1 = *(const float4*)(C + 512 + kq);
  float4 v0 = *(const float4*)(C + 640 + kq);
  float4 v1 = *(const float4*)(C + 768 + kq);
  float4 cb = *(const float4*)(C + 896 + kq);
  float4 o;
  o.x = fmaf(s.x, u0.x, fmaf(s.y, u1.x, fmaf(s0t, v0.x, fmaf(s1t, v1.x, cb.x))));
  o.y = fmaf(s.x, u0.y, fmaf(s.y, u1.y, fmaf(s0t, v0.y, fmaf(s1t, v1.y, cb.y))));
  o.z = fmaf(s.x, u0.z, fmaf(s.y, u1.z, fmaf(s0t, v0.z, fmaf(s1t, v1.z, cb.z))));
  o.w = fmaf(s.x, u0.w, fmaf(s.y, u1.w, fmaf(s0t, v0.w, fmaf(s1t, v1.w, cb.w))));
  *(float4*)(out + n * 128 + kq) = o;
}

extern "C" void kernel_launch(void* const* d_in, const int* in_sizes, int n_in,
                              void* d_out, int out_size, void* d_ws, size_t ws_size,
                              hipStream_t stream) {
  const float* x        = (const float*)d_in[0];
  const int*   ei       = (const int*)d_in[1];
  const float* ea       = (const float*)d_in[2];
  const int*   tgt      = (const int*)d_in[3];
  const float* W_l      = (const float*)d_in[4];
  const float* b_l      = (const float*)d_in[5];
  const float* W_r      = (const float*)d_in[6];
  const float* b_r      = (const float*)d_in[7];
  const float* W_e      = (const float*)d_in[8];
  const float* att      = (const float*)d_in[9];
  const float* bias_out = (const float*)d_in[10];
  const float* W_fc     = (const float*)d_in[11];
  const float* b_fc     = (const float*)d_in[12];

  const int N = in_sizes[0];
  const int E = in_sizes[2];
  const int NB = (N + NPB - 1) / NPB;          // 782 buckets
  const int S_BLOCKS = (E + EPB - 1) / EPB;    // 782 bin blocks

  const size_t sz_rec  = (size_t)S_BLOCKS * EPB * 16;
  const size_t sz_offs = (size_t)(NB + 1) * S_BLOCKS * 4;
  const size_t sz_S    = (size_t)2 * N * 4;
  const size_t sz_C    = 4608;
  // pick the largest P in {4,2,1} whose partial slab fits the workspace
  int P = 4;
  while (P > 1 &&
         sz_rec + sz_offs + sz_S + sz_C + (size_t)NB * P * NPB * 6 * 4 > ws_size)
    P >>= 1;
  const int SPP = (S_BLOCKS + P - 1) / P;      // segments per part (196 @ P=4)

  char* p = (char*)d_ws;
  int4*  rec   = (int4*)p;                      p += sz_rec;
  int*   offsT = (int*)p;                       p += sz_offs;
  float* S     = (float*)p;                     p += sz_S;
  float* C     = (float*)p;                     p += sz_C;
  float* Spart = (float*)p;

  k_prep<<<1, 128, 0, stream>>>((const unsigned int*)ei, att, W_l, b_l, b_r,
                                bias_out, W_fc, b_fc, C);
  k_bin<<<S_BLOCKS, TB, 0, stream>>>(x, ei, ea, W_l, W_r, W_e, C,
                                     rec, offsT, NB, S_BLOCKS, E);
  k_reduce<<<dim3(NB, P), TB, 0, stream>>>(rec, offsT, Spart, S_BLOCKS, SPP);
  k_fin<<<(N + 255) / 256, 256, 0, stream>>>(x, W_l, W_r, W_e, C, Spart, S, N, P);
  k_out<<<(N * 32 + 255) / 256, 256, 0, stream>>>(S, C, tgt, (float*)d_out, N);
}

// Round 3
// 232.985 us; speedup vs baseline: 1.0925x; 1.0925x over previous
//
#include <hip/hip_runtime.h>
#include <math.h>

// GATv2 (in_ch=1, edge_dim=1, H=2, C=64) + fc, collapsed to rank-1/rank-2 algebra.
//
// Round 8: fix round-7's scratch-spill regression. rocprof showed k_reduce
// WRITE_SIZE 94 MB vs 9.6 MB algorithmic -> register spills from the
// l4[4]/rb4[4]/bs4[4] arrays under __launch_bounds__(TB,8). Rewrite k_reduce
// with 1-2 NAMED scalar segments per thread (SPP<=512 invariant, P>=2) and
// relax to __launch_bounds__(TB,4) (minimum, not cap). ~20 live regs, no
// indexed arrays, no spill path.
//
// ws: rec[S_BLOCKS*2048] int4 | offsT[(NB+1)*S_BLOCKS] int | S[2N] f32 |
//     C[1152] f32 | Spart[NB*P*128*6] f32

#define LRELU_A1 0.6f   // leakyrelu(v) = 0.6 v + 0.4 |v|  (slope 0.2)
#define LRELU_A2 0.4f
#define TB       256
#define EPB      2048   // edges per bin block
#define NPB      128    // nodes per bucket (dst>>7)
#define NB_MAX   1024
#define LUTSZ    2048   // record-index LUT entries per window

__global__ void k_prep(const unsigned int* __restrict__ ei,
                       const float* __restrict__ att,
                       const float* __restrict__ W_l,
                       const float* __restrict__ b_l, const float* __restrict__ b_r,
                       const float* __restrict__ bias_out,
                       const float* __restrict__ W_fc, const float* __restrict__ b_fc,
                       float* __restrict__ C) {
  int j = threadIdx.x;
  unsigned long long nz = __ballot(j < 32 && ei[2 * j + 1] != 0u);
  if (j == 0) ((int*)C)[1024] = (nz == 0ull) ? 1 : 0;   // 1 => int64 indices
  if (j >= 128) return;
  float a = att[j];
  C[j] = LRELU_A1 * a;          // A1
  C[128 + j] = LRELU_A2 * a;    // A2
  C[256 + j] = b_l[j] + b_r[j]; // BASE
  const float* wrow = W_fc + j * 256;
  float u0 = 0.f, u1 = 0.f, v0 = 0.f, v1 = 0.f, cb = b_fc[j];
  for (int c = 0; c < 64; c++) {
    u0 = fmaf(W_l[c],      wrow[c],       u0);
    u1 = fmaf(W_l[64 + c], wrow[64 + c],  u1);
    v0 = fmaf(W_l[c],      wrow[128 + c], v0);
    v1 = fmaf(W_l[64 + c], wrow[192 + c], v1);
  }
  for (int t = 0; t < 128; t++) {
    float gb = b_l[t] + bias_out[t];
    cb = fmaf(gb, wrow[t] + wrow[128 + t], cb);
  }
  C[384 + j] = u0;  // U0
  C[512 + j] = u1;  // U1
  C[640 + j] = v0;  // V0
  C[768 + j] = v1;  // V1
  C[896 + j] = cb;  // CB
}

#define CH_STEP(comp, ACC, i)                                                      \
  do {                                                                             \
    float v_ = fmaf(xs8[i], wl.comp, fmaf(xt8[i], wr.comp, fmaf(ae8[i], we.comp, bb.comp))); \
    ACC[i] = fmaf(a2.comp, fabsf(v_), fmaf(a1.comp, v_, ACC[i]));                  \
  } while (0)

__global__ __launch_bounds__(TB, 4) void k_bin(
    const float* __restrict__ x, const int* __restrict__ ei,
    const float* __restrict__ ea,
    const float* __restrict__ WL, const float* __restrict__ WR,
    const float* __restrict__ WE, const float* __restrict__ C,
    int4* __restrict__ rec, int* __restrict__ offsT,
    int NB, int S_BLOCKS, int E) {
  __shared__ int cnt[NB_MAX];
  __shared__ int pfx[NB_MAX + 1];
  __shared__ int sc[TB];
  const int tid = threadIdx.x;
  for (int i = tid; i < NB_MAX; i += TB) cnt[i] = 0;
  __syncthreads();

  const int e0 = blockIdx.x * EPB;
  const bool w64 = ((const int*)C)[1024] != 0;
  const float* A1 = C;
  const float* A2 = C + 128;
  const float* BASE = C + 256;

  int de8[8];
  float ae8[8], xs8[8], xt8[8];
  bool ok[8];
#pragma unroll
  for (int i = 0; i < 8; i++) {
    int e = e0 + i * TB + tid;   // coalesced per round
    ok[i] = (e < E);
    int ee = ok[i] ? e : 0;
    int s_ = w64 ? ei[2 * ee] : ei[ee];
    int d_ = w64 ? ei[2 * (E + ee)] : ei[E + ee];
    de8[i] = d_;
    ae8[i] = ea[ee];
    xs8[i] = x[s_];
    xt8[i] = x[d_];
  }
  float acc0[8] = {0.f, 0.f, 0.f, 0.f, 0.f, 0.f, 0.f, 0.f};
  float acc1[8] = {0.f, 0.f, 0.f, 0.f, 0.f, 0.f, 0.f, 0.f};
#pragma unroll 2
  for (int jb = 0; jb < 64; jb += 4) {
    float4 wl = *(const float4*)(WL + jb);
    float4 wr = *(const float4*)(WR + jb);
    float4 we = *(const float4*)(WE + jb);
    float4 bb = *(const float4*)(BASE + jb);
    float4 a1 = *(const float4*)(A1 + jb);
    float4 a2 = *(const float4*)(A2 + jb);
#pragma unroll
    for (int i = 0; i < 8; i++) {
      CH_STEP(x, acc0, i); CH_STEP(y, acc0, i); CH_STEP(z, acc0, i); CH_STEP(w, acc0, i);
    }
  }
#pragma unroll 2
  for (int jb = 64; jb < 128; jb += 4) {
    float4 wl = *(const float4*)(WL + jb);
    float4 wr = *(const float4*)(WR + jb);
    float4 we = *(const float4*)(WE + jb);
    float4 bb = *(const float4*)(BASE + jb);
    float4 a1 = *(const float4*)(A1 + jb);
    float4 a2 = *(const float4*)(A2 + jb);
#pragma unroll
    for (int i = 0; i < 8; i++) {
      CH_STEP(x, acc1, i); CH_STEP(y, acc1, i); CH_STEP(z, acc1, i); CH_STEP(w, acc1, i);
    }
  }
  // payload -> registers; claim slots in LDS
  int b8[8], slot8[8], p0[8], p1[8], p2[8], p3[8];
#pragma unroll
  for (int i = 0; i < 8; i++) {
    int d_ = de8[i];
    b8[i] = d_ >> 7;
    p0[i] = __float_as_int(__expf(acc0[i]));
    p1[i] = __float_as_int(__expf(acc1[i]));
    p2[i] = __float_as_int(xs8[i]);
    p3[i] = (int)((__float_as_uint(ae8[i]) & ~127u) | (unsigned)(d_ & 127));
    slot8[i] = ok[i] ? atomicAdd(&cnt[b8[i]], 1) : 0;
  }
  __syncthreads();
  // two-level exclusive scan of cnt[0..NB)
  int l4[4], mysum = 0;
#pragma unroll
  for (int j = 0; j < 4; j++) {
    int idx = tid * 4 + j;
    l4[j] = (idx < NB) ? cnt[idx] : 0;
    mysum += l4[j];
  }
  sc[tid] = mysum;
  __syncthreads();
  for (int st = 1; st < TB; st <<= 1) {
    int v = (tid >= st) ? sc[tid - st] : 0;
    __syncthreads();
    sc[tid] += v;
    __syncthreads();
  }
  int run = sc[tid] - mysum;
#pragma unroll
  for (int j = 0; j < 4; j++) {
    int idx = tid * 4 + j;
    if (idx < NB) { pfx[idx] = run; run += l4[j]; }
  }
  if (tid == 0) pfx[NB] = sc[TB - 1];
  __syncthreads();
  for (int b = tid; b <= NB; b += TB)
    offsT[(size_t)b * S_BLOCKS + blockIdx.x] = pfx[b];
  // direct-indexed drain from registers (random within 32KB block region; L2-local)
  int4* myrec = rec + (size_t)blockIdx.x * EPB;
#pragma unroll
  for (int i = 0; i < 8; i++) {
    if (ok[i]) myrec[pfx[b8[i]] + slot8[i]] = make_int4(p0[i], p1[i], p2[i], p3[i]);
  }
}

// One block per (bucket, part). part covers segments s in
// [part*SPP, min((part+1)*SPP, S_BLOCKS)), with SPP <= 2*TB (host invariant).
// Thread tid owns segment tid (A) and tid+TB (B) -- named scalars only, no
// indexed arrays -> no spill path. Gather via LDS record-index LUT; writes
// 128x6 partials to Spart.
__global__ __launch_bounds__(TB, 4) void k_reduce(
    const int4* __restrict__ rec, const int* __restrict__ offsT,
    float* __restrict__ Spart, int S_BLOCKS, int SPP) {
  __shared__ float lacc[NPB * 7];      // stride 7, bank-friendly
  __shared__ int sc[TB];
  __shared__ int lut[LUTSZ];
  const int tid = threadIdx.x;
  const int b = blockIdx.x;            // bucket
  const int part = blockIdx.y;
  for (int i = tid; i < NPB * 7; i += TB) lacc[i] = 0.f;

  // segment A = part*SPP + tid, segment B = part*SPP + tid + TB
  const int sA = part * SPP + tid;
  const int sB = sA + TB;
  int stA = 0, lenA = 0, stB = 0, lenB = 0;
  if (tid < SPP && sA < S_BLOCKS) {
    stA  = offsT[(size_t)b * S_BLOCKS + sA];
    lenA = offsT[(size_t)(b + 1) * S_BLOCKS + sA] - stA;
  }
  if (TB + tid < SPP && sB < S_BLOCKS) {
    stB  = offsT[(size_t)b * S_BLOCKS + sB];
    lenB = offsT[(size_t)(b + 1) * S_BLOCKS + sB] - stB;
  }
  const int rbA = sA * EPB + stA;      // global rec index of segment A start
  const int rbB = sB * EPB + stB;
  const int mysum = lenA + lenB;
  sc[tid] = mysum;
  __syncthreads();
  for (int d = 1; d < TB; d <<= 1) {
    int v = (tid >= d) ? sc[tid - d] : 0;
    __syncthreads();
    sc[tid] += v;
    __syncthreads();
  }
  const int T = sc[TB - 1];
  const int bsA = sc[tid] - mysum;     // this thread's strip: [bsA, bsA+lenA+lenB)
  const int bsB = bsA + lenA;

  for (int w0 = 0; w0 < T; w0 += LUTSZ) {
    const int w1 = min(w0 + LUTSZ, T);
    // fill lut[w0..w1): each segment-owner scatters its records' rec indices
    {
      int lo = max(bsA, w0), hi = min(bsA + lenA, w1);
      for (int k = lo; k < hi; k++) lut[k - w0] = rbA + (k - bsA);
      lo = max(bsB, w0); hi = min(bsB + lenB, w1);
      for (int k = lo; k < hi; k++) lut[k - w0] = rbB + (k - bsB);
    }
    __syncthreads();
    for (int i = w0 + tid; i < w1; i += TB) {
      int4 r = rec[(size_t)(unsigned)lut[i - w0]];
      float e0v = __int_as_float(r.x);
      float e1v = __int_as_float(r.y);
      float xsv = __int_as_float(r.z);
      unsigned eab = (unsigned)r.w;
      float* a = lacc + (int)(eab & 127u) * 7;
      float aev = __uint_as_float(eab & ~127u);
      atomicAdd(a + 0, e0v);
      atomicAdd(a + 1, e0v * xsv);
      atomicAdd(a + 2, e1v);
      atomicAdd(a + 3, e1v * xsv);
      atomicAdd(a + 4, aev);
      atomicAdd(a + 5, 1.0f);
    }
    __syncthreads();
  }
  // drain partials: 768 floats, coalesced
  float* out = Spart + ((size_t)b * gridDim.y + part) * (NPB * 6);
  for (int u = tid; u < NPB * 6; u += TB)
    out[u] = lacc[(u / 6) * 7 + (u % 6)];
}

// Sum the P partials per node, then fused self-loop + S finalize.
__global__ __launch_bounds__(256) void k_fin(
    const float* __restrict__ x,
    const float* __restrict__ WL, const float* __restrict__ WR,
    const float* __restrict__ WE, const float* __restrict__ C,
    const float* __restrict__ Spart, float* __restrict__ S,
    int N, int P) {
  int n = blockIdx.x * blockDim.x + threadIdx.x;
  if (n >= N) return;
  int b = n >> 7, t = n & 127;
  const float* q0 = Spart + ((size_t)b * P) * (NPB * 6) + t * 6;
  float den0 = 0.f, num0 = 0.f, den1 = 0.f, num1 = 0.f, asum = 0.f, cntv = 0.f;
  for (int p = 0; p < P; p++) {
    const float* q = q0 + (size_t)p * (NPB * 6);
    float2 v0 = *(const float2*)(q);
    float2 v1 = *(const float2*)(q + 2);
    float2 v2 = *(const float2*)(q + 4);
    den0 += v0.x; num0 += v0.y;
    den1 += v1.x; num1 += v1.y;
    asum += v2.x; cntv += v2.y;
  }
  const float* A1 = C;
  const float* A2 = C + 128;
  const float* BASE = C + 256;
  float xn = x[n];
  float am = asum / fmaxf(cntv, 1.0f);
  float acc0 = 0.f, acc1 = 0.f;
#pragma unroll 4
  for (int jb = 0; jb < 64; jb += 4) {
    float4 wl = *(const float4*)(WL + jb);
    float4 wr = *(const float4*)(WR + jb);
    float4 we = *(const float4*)(WE + jb);
    float4 bb = *(const float4*)(BASE + jb);
    float4 a1 = *(const float4*)(A1 + jb);
    float4 a2 = *(const float4*)(A2 + jb);
    float v;
    v = fmaf(xn, wl.x + wr.x, fmaf(am, we.x, bb.x)); acc0 = fmaf(a2.x, fabsf(v), fmaf(a1.x, v, acc0));
    v = fmaf(xn, wl.y + wr.y, fmaf(am, we.y, bb.y)); acc0 = fmaf(a2.y, fabsf(v), fmaf(a1.y, v, acc0));
    v = fmaf(xn, wl.z + wr.z, fmaf(am, we.z, bb.z)); acc0 = fmaf(a2.z, fabsf(v), fmaf(a1.z, v, acc0));
    v = fmaf(xn, wl.w + wr.w, fmaf(am, we.w, bb.w)); acc0 = fmaf(a2.w, fabsf(v), fmaf(a1.w, v, acc0));
  }
#pragma unroll 4
  for (int jb = 64; jb < 128; jb += 4) {
    float4 wl = *(const float4*)(WL + jb);
    float4 wr = *(const float4*)(WR + jb);
    float4 we = *(const float4*)(WE + jb);
    float4 bb = *(const float4*)(BASE + jb);
    float4 a1 = *(const float4*)(A1 + jb);
    float4 a2 = *(const float4*)(A2 + jb);
    float v;
    v = fmaf(xn, wl.x + wr.x, fmaf(am, we.x, bb.x)); acc1 = fmaf(a2.x, fabsf(v), fmaf(a1.x, v, acc1));
    v = fmaf(xn, wl.y + wr.y, fmaf(am, we.y, bb.y)); acc1 = fmaf(a2.y, fabsf(v), fmaf(a1.y, v, acc1));
    v = fmaf(xn, wl.z + wr.z, fmaf(am, we.z, bb.z)); acc1 = fmaf(a2.z, fabsf(v), fmaf(a1.z, v, acc1));
    v = fmaf(xn, wl.w + wr.w, fmaf(am, we.w, bb.w)); acc1 = fmaf(a2.w, fabsf(v), fmaf(a1.w, v, acc1));
  }
  float s0 = __expf(acc0), s1 = __expf(acc1);
  float2 sv;
  sv.x = (num0 + s0 * xn) / (den0 + s0);
  sv.y = (num1 + s1 * xn) / (den1 + s1);
  *(float2*)(S + 2 * n) = sv;
}

__global__ __launch_bounds__(256) void k_out(
    const float* __restrict__ S, const float* __restrict__ C,
    const int* __restrict__ tgtp, float* __restrict__ out, int N) {
  int g = blockIdx.x * blockDim.x + threadIdx.x;
  if (g >= N * 32) return;
  int n = g >> 5;
  int kq = (g & 31) * 4;
  int T = tgtp[0];  // low word valid for int32 and little-endian int64
  float s0t = S[2 * T], s1t = S[2 * T + 1];
  float2 s = *(const float2*)(S + 2 * n);
  float4 u0 = *(const float4*)(C + 384 + kq);
  float4 u1 = *(const float4*)(C + 512 + kq);
  float4 v0 = *(const float4*)(C + 640 + kq);
  float4 v1 = *(const float4*)(C + 768 + kq);
  float4 cb = *(const float4*)(C + 896 + kq);
  float4 o;
  o.x = fmaf(s.x, u0.x, fmaf(s.y, u1.x, fmaf(s0t, v0.x, fmaf(s1t, v1.x, cb.x))));
  o.y = fmaf(s.x, u0.y, fmaf(s.y, u1.y, fmaf(s0t, v0.y, fmaf(s1t, v1.y, cb.y))));
  o.z = fmaf(s.x, u0.z, fmaf(s.y, u1.z, fmaf(s0t, v0.z, fmaf(s1t, v1.z, cb.z))));
  o.w = fmaf(s.x, u0.w, fmaf(s.y, u1.w, fmaf(s0t, v0.w, fmaf(s1t, v1.w, cb.w))));
  *(float4*)(out + n * 128 + kq) = o;
}

extern "C" void kernel_launch(void* const* d_in, const int* in_sizes, int n_in,
                              void* d_out, int out_size, void* d_ws, size_t ws_size,
                              hipStream_t stream) {
  const float* x        = (const float*)d_in[0];
  const int*   ei       = (const int*)d_in[1];
  const float* ea       = (const float*)d_in[2];
  const int*   tgt      = (const int*)d_in[3];
  const float* W_l      = (const float*)d_in[4];
  const float* b_l      = (const float*)d_in[5];
  const float* W_r      = (const float*)d_in[6];
  const float* b_r      = (const float*)d_in[7];
  const float* W_e      = (const float*)d_in[8];
  const float* att      = (const float*)d_in[9];
  const float* bias_out = (const float*)d_in[10];
  const float* W_fc     = (const float*)d_in[11];
  const float* b_fc     = (const float*)d_in[12];

  const int N = in_sizes[0];
  const int E = in_sizes[2];
  const int NB = (N + NPB - 1) / NPB;          // 782 buckets
  const int S_BLOCKS = (E + EPB - 1) / EPB;    // 782 bin blocks

  const size_t sz_rec  = (size_t)S_BLOCKS * EPB * 16;
  const size_t sz_offs = (size_t)(NB + 1) * S_BLOCKS * 4;
  const size_t sz_S    = (size_t)2 * N * 4;
  const size_t sz_C    = 4608;
  // largest P in {4,2} whose partial slab fits; SPP must stay <= 2*TB (=512)
  int P = 4;
  while (P > 2 &&
         sz_rec + sz_offs + sz_S + sz_C + (size_t)NB * P * NPB * 6 * 4 > ws_size)
    P >>= 1;
  const int SPP = (S_BLOCKS + P - 1) / P;      // 196 @ P=4, 391 @ P=2

  char* p = (char*)d_ws;
  int4*  rec   = (int4*)p;                      p += sz_rec;
  int*   offsT = (int*)p;                       p += sz_offs;
  float* S     = (float*)p;                     p += sz_S;
  float* C     = (float*)p;                     p += sz_C;
  float* Spart = (float*)p;

  k_prep<<<1, 128, 0, stream>>>((const unsigned int*)ei, att, W_l, b_l, b_r,
                                bias_out, W_fc, b_fc, C);
  k_bin<<<S_BLOCKS, TB, 0, stream>>>(x, ei, ea, W_l, W_r, W_e, C,
                                     rec, offsT, NB, S_BLOCKS, E);
  k_reduce<<<dim3(NB, P), TB, 0, stream>>>(rec, offsT, Spart, S_BLOCKS, SPP);
  k_fin<<<(N + 255) / 256, 256, 0, stream>>>(x, W_l, W_r, W_e, C, Spart, S, N, P);
  k_out<<<(N * 32 + 255) / 256, 256, 0, stream>>>(S, C, tgt, (float*)d_out, N);
}

// Round 4
// 207.462 us; speedup vs baseline: 1.2270x; 1.1230x over previous
//
#include <hip/hip_runtime.h>
#include <math.h>

// GATv2 (in_ch=1, edge_dim=1, H=2, C=64) + fc, collapsed to rank-1/rank-2 algebra.
//
// Round 9: k_reduce accumulate rebuilt as windowed counting-sort + register
// reduction (zero accumulate atomics). Round-8 counters: occ 59.6%, VALU 6.9%,
// HBM 12% -> waves idle on the LDS f32-RMW pipe (6 atomics/record ~ 20-25 us
// of per-CU LDS pipe). New scheme per 512-record window: histogram node key
// (1x ds_add_u32), wave-0 shfl scan of 128 counts, claim+scatter into sorted
// LDS buffer (1x ds_add_rtn_u32 + b128 write), then thread n<128 walks node
// n's contiguous run accumulating 6 sums in REGISTERS. P 4->8 (grid 6256)
// smooths residency (1.5 -> 3 fill rounds) and halves per-block T.
//
// ws: rec[S_BLOCKS*2048] int4 | offsT[(NB+1)*S_BLOCKS] int | S[2N] f32 |
//     C[1152] f32 | Spart[NB*P*128*6] f32

#define LRELU_A1 0.6f   // leakyrelu(v) = 0.6 v + 0.4 |v|  (slope 0.2)
#define LRELU_A2 0.4f
#define TB       256
#define EPB      2048   // edges per bin block
#define NPB      128    // nodes per bucket (dst>>7)
#define NB_MAX   1024
#define SW       512    // sort window (records)

__global__ void k_prep(const unsigned int* __restrict__ ei,
                       const float* __restrict__ att,
                       const float* __restrict__ W_l,
                       const float* __restrict__ b_l, const float* __restrict__ b_r,
                       const float* __restrict__ bias_out,
                       const float* __restrict__ W_fc, const float* __restrict__ b_fc,
                       float* __restrict__ C) {
  int j = threadIdx.x;
  unsigned long long nz = __ballot(j < 32 && ei[2 * j + 1] != 0u);
  if (j == 0) ((int*)C)[1024] = (nz == 0ull) ? 1 : 0;   // 1 => int64 indices
  if (j >= 128) return;
  float a = att[j];
  C[j] = LRELU_A1 * a;          // A1
  C[128 + j] = LRELU_A2 * a;    // A2
  C[256 + j] = b_l[j] + b_r[j]; // BASE
  const float* wrow = W_fc + j * 256;
  float u0 = 0.f, u1 = 0.f, v0 = 0.f, v1 = 0.f, cb = b_fc[j];
  for (int c = 0; c < 64; c++) {
    u0 = fmaf(W_l[c],      wrow[c],       u0);
    u1 = fmaf(W_l[64 + c], wrow[64 + c],  u1);
    v0 = fmaf(W_l[c],      wrow[128 + c], v0);
    v1 = fmaf(W_l[64 + c], wrow[192 + c], v1);
  }
  for (int t = 0; t < 128; t++) {
    float gb = b_l[t] + bias_out[t];
    cb = fmaf(gb, wrow[t] + wrow[128 + t], cb);
  }
  C[384 + j] = u0;  // U0
  C[512 + j] = u1;  // U1
  C[640 + j] = v0;  // V0
  C[768 + j] = v1;  // V1
  C[896 + j] = cb;  // CB
}

#define CH_STEP(comp, ACC, i)                                                      \
  do {                                                                             \
    float v_ = fmaf(xs8[i], wl.comp, fmaf(xt8[i], wr.comp, fmaf(ae8[i], we.comp, bb.comp))); \
    ACC[i] = fmaf(a2.comp, fabsf(v_), fmaf(a1.comp, v_, ACC[i]));                  \
  } while (0)

__global__ __launch_bounds__(TB, 4) void k_bin(
    const float* __restrict__ x, const int* __restrict__ ei,
    const float* __restrict__ ea,
    const float* __restrict__ WL, const float* __restrict__ WR,
    const float* __restrict__ WE, const float* __restrict__ C,
    int4* __restrict__ rec, int* __restrict__ offsT,
    int NB, int S_BLOCKS, int E) {
  __shared__ int cnt[NB_MAX];
  __shared__ int pfx[NB_MAX + 1];
  __shared__ int sc[TB];
  const int tid = threadIdx.x;
  for (int i = tid; i < NB_MAX; i += TB) cnt[i] = 0;
  __syncthreads();

  const int e0 = blockIdx.x * EPB;
  const bool w64 = ((const int*)C)[1024] != 0;
  const float* A1 = C;
  const float* A2 = C + 128;
  const float* BASE = C + 256;

  int de8[8];
  float ae8[8], xs8[8], xt8[8];
  bool ok[8];
#pragma unroll
  for (int i = 0; i < 8; i++) {
    int e = e0 + i * TB + tid;   // coalesced per round
    ok[i] = (e < E);
    int ee = ok[i] ? e : 0;
    int s_ = w64 ? ei[2 * ee] : ei[ee];
    int d_ = w64 ? ei[2 * (E + ee)] : ei[E + ee];
    de8[i] = d_;
    ae8[i] = ea[ee];
    xs8[i] = x[s_];
    xt8[i] = x[d_];
  }
  float acc0[8] = {0.f, 0.f, 0.f, 0.f, 0.f, 0.f, 0.f, 0.f};
  float acc1[8] = {0.f, 0.f, 0.f, 0.f, 0.f, 0.f, 0.f, 0.f};
#pragma unroll 2
  for (int jb = 0; jb < 64; jb += 4) {
    float4 wl = *(const float4*)(WL + jb);
    float4 wr = *(const float4*)(WR + jb);
    float4 we = *(const float4*)(WE + jb);
    float4 bb = *(const float4*)(BASE + jb);
    float4 a1 = *(const float4*)(A1 + jb);
    float4 a2 = *(const float4*)(A2 + jb);
#pragma unroll
    for (int i = 0; i < 8; i++) {
      CH_STEP(x, acc0, i); CH_STEP(y, acc0, i); CH_STEP(z, acc0, i); CH_STEP(w, acc0, i);
    }
  }
#pragma unroll 2
  for (int jb = 64; jb < 128; jb += 4) {
    float4 wl = *(const float4*)(WL + jb);
    float4 wr = *(const float4*)(WR + jb);
    float4 we = *(const float4*)(WE + jb);
    float4 bb = *(const float4*)(BASE + jb);
    float4 a1 = *(const float4*)(A1 + jb);
    float4 a2 = *(const float4*)(A2 + jb);
#pragma unroll
    for (int i = 0; i < 8; i++) {
      CH_STEP(x, acc1, i); CH_STEP(y, acc1, i); CH_STEP(z, acc1, i); CH_STEP(w, acc1, i);
    }
  }
  // payload -> registers; claim slots in LDS
  int b8[8], slot8[8], p0[8], p1[8], p2[8], p3[8];
#pragma unroll
  for (int i = 0; i < 8; i++) {
    int d_ = de8[i];
    b8[i] = d_ >> 7;
    p0[i] = __float_as_int(__expf(acc0[i]));
    p1[i] = __float_as_int(__expf(acc1[i]));
    p2[i] = __float_as_int(xs8[i]);
    p3[i] = (int)((__float_as_uint(ae8[i]) & ~127u) | (unsigned)(d_ & 127));
    slot8[i] = ok[i] ? atomicAdd(&cnt[b8[i]], 1) : 0;
  }
  __syncthreads();
  // two-level exclusive scan of cnt[0..NB)
  int l4[4], mysum = 0;
#pragma unroll
  for (int j = 0; j < 4; j++) {
    int idx = tid * 4 + j;
    l4[j] = (idx < NB) ? cnt[idx] : 0;
    mysum += l4[j];
  }
  sc[tid] = mysum;
  __syncthreads();
  for (int st = 1; st < TB; st <<= 1) {
    int v = (tid >= st) ? sc[tid - st] : 0;
    __syncthreads();
    sc[tid] += v;
    __syncthreads();
  }
  int run = sc[tid] - mysum;
#pragma unroll
  for (int j = 0; j < 4; j++) {
    int idx = tid * 4 + j;
    if (idx < NB) { pfx[idx] = run; run += l4[j]; }
  }
  if (tid == 0) pfx[NB] = sc[TB - 1];
  __syncthreads();
  for (int b = tid; b <= NB; b += TB)
    offsT[(size_t)b * S_BLOCKS + blockIdx.x] = pfx[b];
  // direct-indexed drain from registers (random within 32KB block region; L2-local)
  int4* myrec = rec + (size_t)blockIdx.x * EPB;
#pragma unroll
  for (int i = 0; i < 8; i++) {
    if (ok[i]) myrec[pfx[b8[i]] + slot8[i]] = make_int4(p0[i], p1[i], p2[i], p3[i]);
  }
}

// One block per (bucket, part). part covers segments s in
// [part*SPP, min((part+1)*SPP, S_BLOCKS)), SPP <= 2*TB (host invariant).
// Thread tid owns segment tid (A) and tid+TB (B) as named scalars (no spill).
// Windowed counting sort by 7-bit node key, then per-node register reduction.
__global__ __launch_bounds__(TB, 4) void k_reduce(
    const int4* __restrict__ rec, const int* __restrict__ offsT,
    float* __restrict__ Spart, int S_BLOCKS, int SPP) {
  __shared__ int4 sorted[SW];          // 8 KB
  __shared__ int lut[SW];              // 2 KB
  __shared__ int sc[TB];               // 1 KB
  __shared__ int cnt[NPB];             // histogram
  __shared__ int pos0[NPB];            // exclusive scan of cnt
  __shared__ int claim[NPB];           // scatter cursor
  const int tid = threadIdx.x;
  const int b = blockIdx.x;            // bucket
  const int part = blockIdx.y;

  // segment A = part*SPP + tid, segment B = part*SPP + tid + TB
  const int sA = part * SPP + tid;
  const int sB = sA + TB;
  int stA = 0, lenA = 0, stB = 0, lenB = 0;
  if (tid < SPP && sA < S_BLOCKS) {
    stA  = offsT[(size_t)b * S_BLOCKS + sA];
    lenA = offsT[(size_t)(b + 1) * S_BLOCKS + sA] - stA;
  }
  if (TB + tid < SPP && sB < S_BLOCKS) {
    stB  = offsT[(size_t)b * S_BLOCKS + sB];
    lenB = offsT[(size_t)(b + 1) * S_BLOCKS + sB] - stB;
  }
  const int rbA = sA * EPB + stA;      // global rec index of segment A start
  const int rbB = sB * EPB + stB;
  const int mysum = lenA + lenB;
  sc[tid] = mysum;
  if (tid < NPB) cnt[tid] = 0;
  __syncthreads();
  for (int d = 1; d < TB; d <<= 1) {
    int v = (tid >= d) ? sc[tid - d] : 0;
    __syncthreads();
    sc[tid] += v;
    __syncthreads();
  }
  const int T = sc[TB - 1];
  const int bsA = sc[tid] - mysum;     // this thread's strip: [bsA, bsA+lenA+lenB)
  const int bsB = bsA + lenA;

  // per-node register accumulators (threads < NPB)
  float r0 = 0.f, r1 = 0.f, r2 = 0.f, r3 = 0.f, r4 = 0.f;
  int rc = 0;

  for (int w0 = 0; w0 < T; w0 += SW) {
    const int w1 = min(w0 + SW, T);
    // fill lut[w0..w1): each segment-owner scatters its records' rec indices
    {
      int lo = max(bsA, w0), hi = min(bsA + lenA, w1);
      for (int k = lo; k < hi; k++) lut[k - w0] = rbA + (k - bsA);
      lo = max(bsB, w0); hi = min(bsB + lenB, w1);
      for (int k = lo; k < hi; k++) lut[k - w0] = rbB + (k - bsB);
    }
    __syncthreads();
    // pass A: histogram node keys (no-return u32 atomic)
    for (int i = w0 + tid; i < w1; i += TB) {
      int4 r = rec[(size_t)(unsigned)lut[i - w0]];
      atomicAdd(&cnt[(int)((unsigned)r.w & 127u)], 1);
    }
    __syncthreads();
    // wave 0: exclusive scan of cnt[0..128) via shfl, init claim cursors
    if (tid < 64) {
      int c0 = cnt[2 * tid], c1 = cnt[2 * tid + 1];
      int s = c0 + c1;
      for (int d = 1; d < 64; d <<= 1) {
        int t = __shfl_up(s, d);
        if (tid >= d) s += t;
      }
      int excl = s - (c0 + c1);
      pos0[2 * tid] = excl;
      pos0[2 * tid + 1] = excl + c0;
      claim[2 * tid] = excl;
      claim[2 * tid + 1] = excl + c0;
    }
    __syncthreads();
    // pass B: re-read (cache-hot), claim sorted slot, scatter into LDS
    for (int i = w0 + tid; i < w1; i += TB) {
      int4 r = rec[(size_t)(unsigned)lut[i - w0]];
      int node = (int)((unsigned)r.w & 127u);
      int slot = atomicAdd(&claim[node], 1);
      sorted[slot] = r;
    }
    __syncthreads();
    // pass C: thread n walks node n's contiguous run, accumulates in regs
    if (tid < NPB) {
      int p = pos0[tid], c = cnt[tid];
      for (int k = 0; k < c; k++) {
        int4 r = sorted[p + k];
        float e0v = __int_as_float(r.x);
        float e1v = __int_as_float(r.y);
        float xsv = __int_as_float(r.z);
        float aev = __uint_as_float((unsigned)r.w & ~127u);
        r0 += e0v;
        r1 += e0v * xsv;
        r2 += e1v;
        r3 += e1v * xsv;
        r4 += aev;
      }
      rc += c;
      cnt[tid] = 0;   // reset for next window (after use)
    }
    __syncthreads();
  }
  // drain: 6 floats per node, contiguous 24 B per thread
  if (tid < NPB) {
    float* out = Spart + ((size_t)b * gridDim.y + part) * (NPB * 6) + tid * 6;
    out[0] = r0; out[1] = r1; out[2] = r2;
    out[3] = r3; out[4] = r4; out[5] = (float)rc;
  }
}

// Sum the P partials per node, then fused self-loop + S finalize.
__global__ __launch_bounds__(256) void k_fin(
    const float* __restrict__ x,
    const float* __restrict__ WL, const float* __restrict__ WR,
    const float* __restrict__ WE, const float* __restrict__ C,
    const float* __restrict__ Spart, float* __restrict__ S,
    int N, int P) {
  int n = blockIdx.x * blockDim.x + threadIdx.x;
  if (n >= N) return;
  int b = n >> 7, t = n & 127;
  const float* q0 = Spart + ((size_t)b * P) * (NPB * 6) + t * 6;
  float den0 = 0.f, num0 = 0.f, den1 = 0.f, num1 = 0.f, asum = 0.f, cntv = 0.f;
  for (int p = 0; p < P; p++) {
    const float* q = q0 + (size_t)p * (NPB * 6);
    float2 v0 = *(const float2*)(q);
    float2 v1 = *(const float2*)(q + 2);
    float2 v2 = *(const float2*)(q + 4);
    den0 += v0.x; num0 += v0.y;
    den1 += v1.x; num1 += v1.y;
    asum += v2.x; cntv += v2.y;
  }
  const float* A1 = C;
  const float* A2 = C + 128;
  const float* BASE = C + 256;
  float xn = x[n];
  float am = asum / fmaxf(cntv, 1.0f);
  float acc0 = 0.f, acc1 = 0.f;
#pragma unroll 4
  for (int jb = 0; jb < 64; jb += 4) {
    float4 wl = *(const float4*)(WL + jb);
    float4 wr = *(const float4*)(WR + jb);
    float4 we = *(const float4*)(WE + jb);
    float4 bb = *(const float4*)(BASE + jb);
    float4 a1 = *(const float4*)(A1 + jb);
    float4 a2 = *(const float4*)(A2 + jb);
    float v;
    v = fmaf(xn, wl.x + wr.x, fmaf(am, we.x, bb.x)); acc0 = fmaf(a2.x, fabsf(v), fmaf(a1.x, v, acc0));
    v = fmaf(xn, wl.y + wr.y, fmaf(am, we.y, bb.y)); acc0 = fmaf(a2.y, fabsf(v), fmaf(a1.y, v, acc0));
    v = fmaf(xn, wl.z + wr.z, fmaf(am, we.z, bb.z)); acc0 = fmaf(a2.z, fabsf(v), fmaf(a1.z, v, acc0));
    v = fmaf(xn, wl.w + wr.w, fmaf(am, we.w, bb.w)); acc0 = fmaf(a2.w, fabsf(v), fmaf(a1.w, v, acc0));
  }
#pragma unroll 4
  for (int jb = 64; jb < 128; jb += 4) {
    float4 wl = *(const float4*)(WL + jb);
    float4 wr = *(const float4*)(WR + jb);
    float4 we = *(const float4*)(WE + jb);
    float4 bb = *(const float4*)(BASE + jb);
    float4 a1 = *(const float4*)(A1 + jb);
    float4 a2 = *(const float4*)(A2 + jb);
    float v;
    v = fmaf(xn, wl.x + wr.x, fmaf(am, we.x, bb.x)); acc1 = fmaf(a2.x, fabsf(v), fmaf(a1.x, v, acc1));
    v = fmaf(xn, wl.y + wr.y, fmaf(am, we.y, bb.y)); acc1 = fmaf(a2.y, fabsf(v), fmaf(a1.y, v, acc1));
    v = fmaf(xn, wl.z + wr.z, fmaf(am, we.z, bb.z)); acc1 = fmaf(a2.z, fabsf(v), fmaf(a1.z, v, acc1));
    v = fmaf(xn, wl.w + wr.w, fmaf(am, we.w, bb.w)); acc1 = fmaf(a2.w, fabsf(v), fmaf(a1.w, v, acc1));
  }
  float s0 = __expf(acc0), s1 = __expf(acc1);
  float2 sv;
  sv.x = (num0 + s0 * xn) / (den0 + s0);
  sv.y = (num1 + s1 * xn) / (den1 + s1);
  *(float2*)(S + 2 * n) = sv;
}

__global__ __launch_bounds__(256) void k_out(
    const float* __restrict__ S, const float* __restrict__ C,
    const int* __restrict__ tgtp, float* __restrict__ out, int N) {
  int g = blockIdx.x * blockDim.x + threadIdx.x;
  if (g >= N * 32) return;
  int n = g >> 5;
  int kq = (g & 31) * 4;
  int T = tgtp[0];  // low word valid for int32 and little-endian int64
  float s0t = S[2 * T], s1t = S[2 * T + 1];
  float2 s = *(const float2*)(S + 2 * n);
  float4 u0 = *(const float4*)(C + 384 + kq);
  float4 u1 = *(const float4*)(C + 512 + kq);
  float4 v0 = *(const float4*)(C + 640 + kq);
  float4 v1 = *(const float4*)(C + 768 + kq);
  float4 cb = *(const float4*)(C + 896 + kq);
  float4 o;
  o.x = fmaf(s.x, u0.x, fmaf(s.y, u1.x, fmaf(s0t, v0.x, fmaf(s1t, v1.x, cb.x))));
  o.y = fmaf(s.x, u0.y, fmaf(s.y, u1.y, fmaf(s0t, v0.y, fmaf(s1t, v1.y, cb.y))));
  o.z = fmaf(s.x, u0.z, fmaf(s.y, u1.z, fmaf(s0t, v0.z, fmaf(s1t, v1.z, cb.z))));
  o.w = fmaf(s.x, u0.w, fmaf(s.y, u1.w, fmaf(s0t, v0.w, fmaf(s1t, v1.w, cb.w))));
  *(float4*)(out + n * 128 + kq) = o;
}

extern "C" void kernel_launch(void* const* d_in, const int* in_sizes, int n_in,
                              void* d_out, int out_size, void* d_ws, size_t ws_size,
                              hipStream_t stream) {
  const float* x        = (const float*)d_in[0];
  const int*   ei       = (const int*)d_in[1];
  const float* ea       = (const float*)d_in[2];
  const int*   tgt      = (const int*)d_in[3];
  const float* W_l      = (const float*)d_in[4];
  const float* b_l      = (const float*)d_in[5];
  const float* W_r      = (const float*)d_in[6];
  const float* b_r      = (const float*)d_in[7];
  const float* W_e      = (const float*)d_in[8];
  const float* att      = (const float*)d_in[9];
  const float* bias_out = (const float*)d_in[10];
  const float* W_fc     = (const float*)d_in[11];
  const float* b_fc     = (const float*)d_in[12];

  const int N = in_sizes[0];
  const int E = in_sizes[2];
  const int NB = (N + NPB - 1) / NPB;          // 782 buckets
  const int S_BLOCKS = (E + EPB - 1) / EPB;    // 782 bin blocks

  const size_t sz_rec  = (size_t)S_BLOCKS * EPB * 16;
  const size_t sz_offs = (size_t)(NB + 1) * S_BLOCKS * 4;
  const size_t sz_S    = (size_t)2 * N * 4;
  const size_t sz_C    = 4608;
  // largest P in {8,4,2} whose partial slab fits; SPP must stay <= 2*TB (=512)
  int P = 8;
  while (P > 2 &&
         sz_rec + sz_offs + sz_S + sz_C + (size_t)NB * P * NPB * 6 * 4 > ws_size)
    P >>= 1;
  const int SPP = (S_BLOCKS + P - 1) / P;      // 98 @ P=8, 196 @ P=4

  char* p = (char*)d_ws;
  int4*  rec   = (int4*)p;                      p += sz_rec;
  int*   offsT = (int*)p;                       p += sz_offs;
  float* S     = (float*)p;                     p += sz_S;
  float* C     = (float*)p;                     p += sz_C;
  float* Spart = (float*)p;

  k_prep<<<1, 128, 0, stream>>>((const unsigned int*)ei, att, W_l, b_l, b_r,
                                bias_out, W_fc, b_fc, C);
  k_bin<<<S_BLOCKS, TB, 0, stream>>>(x, ei, ea, W_l, W_r, W_e, C,
                                     rec, offsT, NB, S_BLOCKS, E);
  k_reduce<<<dim3(NB, P), TB, 0, stream>>>(rec, offsT, Spart, S_BLOCKS, SPP);
  k_fin<<<(N + 255) / 256, 256, 0, stream>>>(x, W_l, W_r, W_e, C, Spart, S, N, P);
  k_out<<<(N * 32 + 255) / 256, 256, 0, stream>>>(S, C, tgt, (float*)d_out, N);
}

// Round 5
// 206.348 us; speedup vs baseline: 1.2336x; 1.0054x over previous
//
#include <hip/hip_runtime.h>
#include <math.h>

// GATv2 (in_ch=1, edge_dim=1, H=2, C=64) + fc, collapsed to rank-1/rank-2 algebra.
//
// Round 10: k_bin occupancy fix (same disease k_reduce had in R5): grid was
// 782 blocks = 3.05/CU -> occ 19.6%, VALU 38%. EPB 2048->1024 (S_BLOCKS
// 1563, 6.1 blocks/CU, 4 edges/thread) and both Hillis-Steele scans (16
// syncthreads each) replaced by wave-shfl scans (1 barrier). k_reduce
// invariants hold: SPP=196<=512 @ P=8, T/part ~256 records.
//
// ws: rec[S_BLOCKS*1024] int4 | offsT[(NB+1)*S_BLOCKS] int | S[2N] f32 |
//     C[1152] f32 | Spart[NB*P*128*6] f32

#define LRELU_A1 0.6f   // leakyrelu(v) = 0.6 v + 0.4 |v|  (slope 0.2)
#define LRELU_A2 0.4f
#define TB       256
#define EPB      1024   // edges per bin block
#define NE       (EPB / TB)  // 4 edges per thread
#define NPB      128    // nodes per bucket (dst>>7)
#define NB_MAX   1024
#define SW       512    // sort window (records)

__global__ void k_prep(const unsigned int* __restrict__ ei,
                       const float* __restrict__ att,
                       const float* __restrict__ W_l,
                       const float* __restrict__ b_l, const float* __restrict__ b_r,
                       const float* __restrict__ bias_out,
                       const float* __restrict__ W_fc, const float* __restrict__ b_fc,
                       float* __restrict__ C) {
  int j = threadIdx.x;
  unsigned long long nz = __ballot(j < 32 && ei[2 * j + 1] != 0u);
  if (j == 0) ((int*)C)[1024] = (nz == 0ull) ? 1 : 0;   // 1 => int64 indices
  if (j >= 128) return;
  float a = att[j];
  C[j] = LRELU_A1 * a;          // A1
  C[128 + j] = LRELU_A2 * a;    // A2
  C[256 + j] = b_l[j] + b_r[j]; // BASE
  const float* wrow = W_fc + j * 256;
  float u0 = 0.f, u1 = 0.f, v0 = 0.f, v1 = 0.f, cb = b_fc[j];
  for (int c = 0; c < 64; c++) {
    u0 = fmaf(W_l[c],      wrow[c],       u0);
    u1 = fmaf(W_l[64 + c], wrow[64 + c],  u1);
    v0 = fmaf(W_l[c],      wrow[128 + c], v0);
    v1 = fmaf(W_l[64 + c], wrow[192 + c], v1);
  }
  for (int t = 0; t < 128; t++) {
    float gb = b_l[t] + bias_out[t];
    cb = fmaf(gb, wrow[t] + wrow[128 + t], cb);
  }
  C[384 + j] = u0;  // U0
  C[512 + j] = u1;  // U1
  C[640 + j] = v0;  // V0
  C[768 + j] = v1;  // V1
  C[896 + j] = cb;  // CB
}

#define CH_STEP(comp, ACC, i)                                                      \
  do {                                                                             \
    float v_ = fmaf(xs8[i], wl.comp, fmaf(xt8[i], wr.comp, fmaf(ae8[i], we.comp, bb.comp))); \
    ACC[i] = fmaf(a2.comp, fabsf(v_), fmaf(a1.comp, v_, ACC[i]));                  \
  } while (0)

__global__ __launch_bounds__(TB, 4) void k_bin(
    const float* __restrict__ x, const int* __restrict__ ei,
    const float* __restrict__ ea,
    const float* __restrict__ WL, const float* __restrict__ WR,
    const float* __restrict__ WE, const float* __restrict__ C,
    int4* __restrict__ rec, int* __restrict__ offsT,
    int NB, int S_BLOCKS, int E) {
  __shared__ int cnt[NB_MAX];
  __shared__ int pfx[NB_MAX + 1];
  __shared__ int wsum[4];
  const int tid = threadIdx.x;
  for (int i = tid; i < NB_MAX; i += TB) cnt[i] = 0;
  __syncthreads();

  const int e0 = blockIdx.x * EPB;
  const bool w64 = ((const int*)C)[1024] != 0;
  const float* A1 = C;
  const float* A2 = C + 128;
  const float* BASE = C + 256;

  int de8[NE];
  float ae8[NE], xs8[NE], xt8[NE];
  bool ok[NE];
#pragma unroll
  for (int i = 0; i < NE; i++) {
    int e = e0 + i * TB + tid;   // coalesced per round
    ok[i] = (e < E);
    int ee = ok[i] ? e : 0;
    int s_ = w64 ? ei[2 * ee] : ei[ee];
    int d_ = w64 ? ei[2 * (E + ee)] : ei[E + ee];
    de8[i] = d_;
    ae8[i] = ea[ee];
    xs8[i] = x[s_];
    xt8[i] = x[d_];
  }
  float acc0[NE], acc1[NE];
#pragma unroll
  for (int i = 0; i < NE; i++) { acc0[i] = 0.f; acc1[i] = 0.f; }
#pragma unroll 2
  for (int jb = 0; jb < 64; jb += 4) {
    float4 wl = *(const float4*)(WL + jb);
    float4 wr = *(const float4*)(WR + jb);
    float4 we = *(const float4*)(WE + jb);
    float4 bb = *(const float4*)(BASE + jb);
    float4 a1 = *(const float4*)(A1 + jb);
    float4 a2 = *(const float4*)(A2 + jb);
#pragma unroll
    for (int i = 0; i < NE; i++) {
      CH_STEP(x, acc0, i); CH_STEP(y, acc0, i); CH_STEP(z, acc0, i); CH_STEP(w, acc0, i);
    }
  }
#pragma unroll 2
  for (int jb = 64; jb < 128; jb += 4) {
    float4 wl = *(const float4*)(WL + jb);
    float4 wr = *(const float4*)(WR + jb);
    float4 we = *(const float4*)(WE + jb);
    float4 bb = *(const float4*)(BASE + jb);
    float4 a1 = *(const float4*)(A1 + jb);
    float4 a2 = *(const float4*)(A2 + jb);
#pragma unroll
    for (int i = 0; i < NE; i++) {
      CH_STEP(x, acc1, i); CH_STEP(y, acc1, i); CH_STEP(z, acc1, i); CH_STEP(w, acc1, i);
    }
  }
  // payload -> registers; claim slots in LDS
  int b8[NE], slot8[NE], p0[NE], p1[NE], p2[NE], p3[NE];
#pragma unroll
  for (int i = 0; i < NE; i++) {
    int d_ = de8[i];
    b8[i] = d_ >> 7;
    p0[i] = __float_as_int(__expf(acc0[i]));
    p1[i] = __float_as_int(__expf(acc1[i]));
    p2[i] = __float_as_int(xs8[i]);
    p3[i] = (int)((__float_as_uint(ae8[i]) & ~127u) | (unsigned)(d_ & 127));
    slot8[i] = ok[i] ? atomicAdd(&cnt[b8[i]], 1) : 0;
  }
  __syncthreads();
  // exclusive scan of cnt[0..NB): per-thread 4 buckets, wave-shfl scan
  int l4[4], mysum = 0;
#pragma unroll
  for (int j = 0; j < 4; j++) {
    int idx = tid * 4 + j;
    l4[j] = (idx < NB) ? cnt[idx] : 0;
    mysum += l4[j];
  }
  const int lane = tid & 63, wv = tid >> 6;
  int inc = mysum;
#pragma unroll
  for (int d = 1; d < 64; d <<= 1) {
    int t = __shfl_up(inc, d);
    if (lane >= d) inc += t;
  }
  if (lane == 63) wsum[wv] = inc;
  __syncthreads();
  int wbase = 0;
#pragma unroll
  for (int w = 0; w < 4; w++) if (w < wv) wbase += wsum[w];
  int run = wbase + inc - mysum;
#pragma unroll
  for (int j = 0; j < 4; j++) {
    int idx = tid * 4 + j;
    if (idx < NB) { pfx[idx] = run; run += l4[j]; }
  }
  if (tid == 0) pfx[NB] = wsum[0] + wsum[1] + wsum[2] + wsum[3];
  __syncthreads();
  for (int b = tid; b <= NB; b += TB)
    offsT[(size_t)b * S_BLOCKS + blockIdx.x] = pfx[b];
  // direct-indexed drain from registers (random within 16KB block region; L2-local)
  int4* myrec = rec + (size_t)blockIdx.x * EPB;
#pragma unroll
  for (int i = 0; i < NE; i++) {
    if (ok[i]) myrec[pfx[b8[i]] + slot8[i]] = make_int4(p0[i], p1[i], p2[i], p3[i]);
  }
}

// One block per (bucket, part). part covers segments s in
// [part*SPP, min((part+1)*SPP, S_BLOCKS)), SPP <= 2*TB (host invariant).
// Thread tid owns segment tid (A) and tid+TB (B) as named scalars (no spill).
// Windowed counting sort by 7-bit node key, then per-node register reduction.
__global__ __launch_bounds__(TB, 4) void k_reduce(
    const int4* __restrict__ rec, const int* __restrict__ offsT,
    float* __restrict__ Spart, int S_BLOCKS, int SPP) {
  __shared__ int4 sorted[SW];          // 8 KB
  __shared__ int lut[SW];              // 2 KB
  __shared__ int cnt[NPB];             // histogram
  __shared__ int pos0[NPB];            // exclusive scan of cnt
  __shared__ int claim[NPB];           // scatter cursor
  __shared__ int wsum[4];
  const int tid = threadIdx.x;
  const int b = blockIdx.x;            // bucket
  const int part = blockIdx.y;

  // segment A = part*SPP + tid, segment B = part*SPP + tid + TB
  const int sA = part * SPP + tid;
  const int sB = sA + TB;
  int stA = 0, lenA = 0, stB = 0, lenB = 0;
  if (tid < SPP && sA < S_BLOCKS) {
    stA  = offsT[(size_t)b * S_BLOCKS + sA];
    lenA = offsT[(size_t)(b + 1) * S_BLOCKS + sA] - stA;
  }
  if (TB + tid < SPP && sB < S_BLOCKS) {
    stB  = offsT[(size_t)b * S_BLOCKS + sB];
    lenB = offsT[(size_t)(b + 1) * S_BLOCKS + sB] - stB;
  }
  const int rbA = sA * EPB + stA;      // global rec index of segment A start
  const int rbB = sB * EPB + stB;
  const int mysum = lenA + lenB;
  if (tid < NPB) cnt[tid] = 0;
  // wave-shfl exclusive scan of per-thread record counts
  const int lane = tid & 63, wv = tid >> 6;
  int inc = mysum;
#pragma unroll
  for (int d = 1; d < 64; d <<= 1) {
    int t = __shfl_up(inc, d);
    if (lane >= d) inc += t;
  }
  if (lane == 63) wsum[wv] = inc;
  __syncthreads();
  int wbase = 0;
#pragma unroll
  for (int w = 0; w < 4; w++) if (w < wv) wbase += wsum[w];
  const int T = wsum[0] + wsum[1] + wsum[2] + wsum[3];
  const int bsA = wbase + inc - mysum; // this thread's strip: [bsA, bsA+lenA+lenB)
  const int bsB = bsA + lenA;

  // per-node register accumulators (threads < NPB)
  float r0 = 0.f, r1 = 0.f, r2 = 0.f, r3 = 0.f, r4 = 0.f;
  int rc = 0;

  for (int w0 = 0; w0 < T; w0 += SW) {
    const int w1 = min(w0 + SW, T);
    // fill lut[w0..w1): each segment-owner scatters its records' rec indices
    {
      int lo = max(bsA, w0), hi = min(bsA + lenA, w1);
      for (int k = lo; k < hi; k++) lut[k - w0] = rbA + (k - bsA);
      lo = max(bsB, w0); hi = min(bsB + lenB, w1);
      for (int k = lo; k < hi; k++) lut[k - w0] = rbB + (k - bsB);
    }
    __syncthreads();
    // pass A: histogram node keys (no-return u32 atomic)
    for (int i = w0 + tid; i < w1; i += TB) {
      int4 r = rec[(size_t)(unsigned)lut[i - w0]];
      atomicAdd(&cnt[(int)((unsigned)r.w & 127u)], 1);
    }
    __syncthreads();
    // wave 0: exclusive scan of cnt[0..128) via shfl, init claim cursors
    if (tid < 64) {
      int c0 = cnt[2 * tid], c1 = cnt[2 * tid + 1];
      int s = c0 + c1;
      for (int d = 1; d < 64; d <<= 1) {
        int t = __shfl_up(s, d);
        if (tid >= d) s += t;
      }
      int excl = s - (c0 + c1);
      pos0[2 * tid] = excl;
      pos0[2 * tid + 1] = excl + c0;
      claim[2 * tid] = excl;
      claim[2 * tid + 1] = excl + c0;
    }
    __syncthreads();
    // pass B: re-read (cache-hot), claim sorted slot, scatter into LDS
    for (int i = w0 + tid; i < w1; i += TB) {
      int4 r = rec[(size_t)(unsigned)lut[i - w0]];
      int node = (int)((unsigned)r.w & 127u);
      int slot = atomicAdd(&claim[node], 1);
      sorted[slot] = r;
    }
    __syncthreads();
    // pass C: thread n walks node n's contiguous run, accumulates in regs
    if (tid < NPB) {
      int p = pos0[tid], c = cnt[tid];
      for (int k = 0; k < c; k++) {
        int4 r = sorted[p + k];
        float e0v = __int_as_float(r.x);
        float e1v = __int_as_float(r.y);
        float xsv = __int_as_float(r.z);
        float aev = __uint_as_float((unsigned)r.w & ~127u);
        r0 += e0v;
        r1 += e0v * xsv;
        r2 += e1v;
        r3 += e1v * xsv;
        r4 += aev;
      }
      rc += c;
      cnt[tid] = 0;   // reset for next window (after use)
    }
    __syncthreads();
  }
  // drain: 6 floats per node, contiguous 24 B per thread
  if (tid < NPB) {
    float* out = Spart + ((size_t)b * gridDim.y + part) * (NPB * 6) + tid * 6;
    out[0] = r0; out[1] = r1; out[2] = r2;
    out[3] = r3; out[4] = r4; out[5] = (float)rc;
  }
}

// Sum the P partials per node, then fused self-loop + S finalize.
__global__ __launch_bounds__(256) void k_fin(
    const float* __restrict__ x,
    const float* __restrict__ WL, const float* __restrict__ WR,
    const float* __restrict__ WE, const float* __restrict__ C,
    const float* __restrict__ Spart, float* __restrict__ S,
    int N, int P) {
  int n = blockIdx.x * blockDim.x + threadIdx.x;
  if (n >= N) return;
  int b = n >> 7, t = n & 127;
  const float* q0 = Spart + ((size_t)b * P) * (NPB * 6) + t * 6;
  float den0 = 0.f, num0 = 0.f, den1 = 0.f, num1 = 0.f, asum = 0.f, cntv = 0.f;
  for (int p = 0; p < P; p++) {
    const float* q = q0 + (size_t)p * (NPB * 6);
    float2 v0 = *(const float2*)(q);
    float2 v1 = *(const float2*)(q + 2);
    float2 v2 = *(const float2*)(q + 4);
    den0 += v0.x; num0 += v0.y;
    den1 += v1.x; num1 += v1.y;
    asum += v2.x; cntv += v2.y;
  }
  const float* A1 = C;
  const float* A2 = C + 128;
  const float* BASE = C + 256;
  float xn = x[n];
  float am = asum / fmaxf(cntv, 1.0f);
  float acc0 = 0.f, acc1 = 0.f;
#pragma unroll 4
  for (int jb = 0; jb < 64; jb += 4) {
    float4 wl = *(const float4*)(WL + jb);
    float4 wr = *(const float4*)(WR + jb);
    float4 we = *(const float4*)(WE + jb);
    float4 bb = *(const float4*)(BASE + jb);
    float4 a1 = *(const float4*)(A1 + jb);
    float4 a2 = *(const float4*)(A2 + jb);
    float v;
    v = fmaf(xn, wl.x + wr.x, fmaf(am, we.x, bb.x)); acc0 = fmaf(a2.x, fabsf(v), fmaf(a1.x, v, acc0));
    v = fmaf(xn, wl.y + wr.y, fmaf(am, we.y, bb.y)); acc0 = fmaf(a2.y, fabsf(v), fmaf(a1.y, v, acc0));
    v = fmaf(xn, wl.z + wr.z, fmaf(am, we.z, bb.z)); acc0 = fmaf(a2.z, fabsf(v), fmaf(a1.z, v, acc0));
    v = fmaf(xn, wl.w + wr.w, fmaf(am, we.w, bb.w)); acc0 = fmaf(a2.w, fabsf(v), fmaf(a1.w, v, acc0));
  }
#pragma unroll 4
  for (int jb = 64; jb < 128; jb += 4) {
    float4 wl = *(const float4*)(WL + jb);
    float4 wr = *(const float4*)(WR + jb);
    float4 we = *(const float4*)(WE + jb);
    float4 bb = *(const float4*)(BASE + jb);
    float4 a1 = *(const float4*)(A1 + jb);
    float4 a2 = *(const float4*)(A2 + jb);
    float v;
    v = fmaf(xn, wl.x + wr.x, fmaf(am, we.x, bb.x)); acc1 = fmaf(a2.x, fabsf(v), fmaf(a1.x, v, acc1));
    v = fmaf(xn, wl.y + wr.y, fmaf(am, we.y, bb.y)); acc1 = fmaf(a2.y, fabsf(v), fmaf(a1.y, v, acc1));
    v = fmaf(xn, wl.z + wr.z, fmaf(am, we.z, bb.z)); acc1 = fmaf(a2.z, fabsf(v), fmaf(a1.z, v, acc1));
    v = fmaf(xn, wl.w + wr.w, fmaf(am, we.w, bb.w)); acc1 = fmaf(a2.w, fabsf(v), fmaf(a1.w, v, acc1));
  }
  float s0 = __expf(acc0), s1 = __expf(acc1);
  float2 sv;
  sv.x = (num0 + s0 * xn) / (den0 + s0);
  sv.y = (num1 + s1 * xn) / (den1 + s1);
  *(float2*)(S + 2 * n) = sv;
}

__global__ __launch_bounds__(256) void k_out(
    const float* __restrict__ S, const float* __restrict__ C,
    const int* __restrict__ tgtp, float* __restrict__ out, int N) {
  int g = blockIdx.x * blockDim.x + threadIdx.x;
  if (g >= N * 32) return;
  int n = g >> 5;
  int kq = (g & 31) * 4;
  int T = tgtp[0];  // low word valid for int32 and little-endian int64
  float s0t = S[2 * T], s1t = S[2 * T + 1];
  float2 s = *(const float2*)(S + 2 * n);
  float4 u0 = *(const float4*)(C + 384 + kq);
  float4 u1 = *(const float4*)(C + 512 + kq);
  float4 v0 = *(const float4*)(C + 640 + kq);
  float4 v1 = *(const float4*)(C + 768 + kq);
  float4 cb = *(const float4*)(C + 896 + kq);
  float4 o;
  o.x = fmaf(s.x, u0.x, fmaf(s.y, u1.x, fmaf(s0t, v0.x, fmaf(s1t, v1.x, cb.x))));
  o.y = fmaf(s.x, u0.y, fmaf(s.y, u1.y, fmaf(s0t, v0.y, fmaf(s1t, v1.y, cb.y))));
  o.z = fmaf(s.x, u0.z, fmaf(s.y, u1.z, fmaf(s0t, v0.z, fmaf(s1t, v1.z, cb.z))));
  o.w = fmaf(s.x, u0.w, fmaf(s.y, u1.w, fmaf(s0t, v0.w, fmaf(s1t, v1.w, cb.w))));
  *(float4*)(out + n * 128 + kq) = o;
}

extern "C" void kernel_launch(void* const* d_in, const int* in_sizes, int n_in,
                              void* d_out, int out_size, void* d_ws, size_t ws_size,
                              hipStream_t stream) {
  const float* x        = (const float*)d_in[0];
  const int*   ei       = (const int*)d_in[1];
  const float* ea       = (const float*)d_in[2];
  const int*   tgt      = (const int*)d_in[3];
  const float* W_l      = (const float*)d_in[4];
  const float* b_l      = (const float*)d_in[5];
  const float* W_r      = (const float*)d_in[6];
  const float* b_r      = (const float*)d_in[7];
  const float* W_e      = (const float*)d_in[8];
  const float* att      = (const float*)d_in[9];
  const float* bias_out = (const float*)d_in[10];
  const float* W_fc     = (const float*)d_in[11];
  const float* b_fc     = (const float*)d_in[12];

  const int N = in_sizes[0];
  const int E = in_sizes[2];
  const int NB = (N + NPB - 1) / NPB;          // 782 buckets
  const int S_BLOCKS = (E + EPB - 1) / EPB;    // 1563 bin blocks

  const size_t sz_rec  = (size_t)S_BLOCKS * EPB * 16;
  const size_t sz_offs = (size_t)(NB + 1) * S_BLOCKS * 4;
  const size_t sz_S    = (size_t)2 * N * 4;
  const size_t sz_C    = 4608;
  // largest P in {8,4,2} whose partial slab fits; SPP must stay <= 2*TB (=512)
  int P = 8;
  while (P > 2 &&
         sz_rec + sz_offs + sz_S + sz_C + (size_t)NB * P * NPB * 6 * 4 > ws_size)
    P >>= 1;
  const int SPP = (S_BLOCKS + P - 1) / P;      // 196 @ P=8, 391 @ P=4

  char* p = (char*)d_ws;
  int4*  rec   = (int4*)p;                      p += sz_rec;
  int*   offsT = (int*)p;                       p += sz_offs;
  float* S     = (float*)p;                     p += sz_S;
  float* C     = (float*)p;                     p += sz_C;
  float* Spart = (float*)p;

  k_prep<<<1, 128, 0, stream>>>((const unsigned int*)ei, att, W_l, b_l, b_r,
                                bias_out, W_fc, b_fc, C);
  k_bin<<<S_BLOCKS, TB, 0, stream>>>(x, ei, ea, W_l, W_r, W_e, C,
                                     rec, offsT, NB, S_BLOCKS, E);
  k_reduce<<<dim3(NB, P), TB, 0, stream>>>(rec, offsT, Spart, S_BLOCKS, SPP);
  k_fin<<<(N + 255) / 256, 256, 0, stream>>>(x, W_l, W_r, W_e, C, Spart, S, N, P);
  k_out<<<(N * 32 + 255) / 256, 256, 0, stream>>>(S, C, tgt, (float*)d_out, N);
}